// Round 12
// baseline (40.142 us; speedup 1.0000x reference)
//
#include <hip/hip_runtime.h>

// y = convT3d(x, weight.sum(oc), stride=2, pad=2, k=5) + sum(bias); out = 6^3 stride-6 max.
// MFMA formulation (verified R6-R11, absmax 0.25): y[2m+t] = sum_{ic,abc} x[ic,m+1-abc]*w[ic,t+2abc]
//   D[16 w-cells x 8 parities] += A[cells x 32ic] * B[32ic x parities], 27 (a,b,c) chunks.
// R12: NO transpose kernel. conv stages A directly from fp32 x (pack bf16 in-kernel, R10 style)
//   with the two R10 traps fixed: (a) XCD-affinity block mapping (blk&7 = xcd; each XCD owns
//   2 images = 4MB = its L2) so the ~2x block redundancy is L2-served, HBM = read-x-once;
//   (b) loads wave-uniform-predicated only + arithmetic halo masking (clamp addr, *0.f) so the
//   allocator cannot sink prefetch loads. Compute/pool core = R11 verbatim.

typedef short v8s __attribute__((ext_vector_type(8)));
typedef float v4f __attribute__((ext_vector_type(4)));
typedef unsigned short ushort_t;

#define CHSTR 16384
#define NSTRIDE (32*CHSTR)
#define Y_N 108000
#define Y_TOT (16*Y_N)
#define XSTR 24
#define ROW_US 1088              // LDS slab row stride: 34 cols x 32 ic

#define WSF_BYTE_OFF 27648u      // Btab = 27*64*8*2 bytes
#define NEED_FUSED (27648u + 4097u*4u)

static __device__ __forceinline__ ushort_t f2bf(float f) {
  unsigned u = __builtin_bit_cast(unsigned, f);
  unsigned r = (u + 0x7FFFu + ((u >> 16) & 1u)) >> 16;
  return (ushort_t)r;
}
static __device__ __forceinline__ unsigned pk2(float a, float b) {
  return (unsigned)f2bf(a) | ((unsigned)f2bf(b) << 16);
}

// ---------------- prep: B fragment table + bias sum (verified R10) ------
__global__ __launch_bounds__(256) void prep_bw(const float* __restrict__ w,
                                               const float* __restrict__ bias,
                                               ushort_t* __restrict__ Btab,
                                               float* __restrict__ wsf) {
  int abc = blockIdx.x;               // a*9 + b*3 + c
  int a = abc / 9, b = (abc / 3) % 3, c = abc % 3;
  int t = threadIdx.x;
  int half = t & 3;
  int l = t >> 2;
  int tt = l & 15, g = l >> 4;
  float v0 = 0.f, v1 = 0.f;
  if (tt < 8) {
    int td = tt & 1, th = (tt >> 1) & 1, tw = tt >> 2;
    int kd = td + 2 * a, kh = th + 2 * b, kw = tw + 2 * c;
    if (kd < 5 && kh < 5 && kw < 5) {
      int off = kd * 25 + kh * 5 + kw;
      const float* wp0 = w + (size_t)(8 * g + 2 * half) * 64 * 125 + off;
      const float* wp1 = wp0 + 64 * 125;
      float s0 = 0.f, s1 = 0.f;
#pragma unroll
      for (int oc = 0; oc < 64; ++oc) { s0 += wp0[oc * 125]; s1 += wp1[oc * 125]; }
      v0 = s0; v1 = s1;
    }
  }
  ((unsigned*)Btab)[(abc * 64 + l) * 4 + half] = (unsigned)f2bf(v0) | ((unsigned)f2bf(v1) << 16);
  if (abc == 0 && t == 0) {
    float bs = 0.f;
    for (int o = 0; o < 64; ++o) bs += bias[o];
    wsf[4096] = bs;
  }
}

// ---------------- fused direct-stage MFMA conv + 6^3 pool ---------------
// 400 blocks = 8 xcd x 2 im x 25 cell; 576 threads = 9 waves (mdl, mh-pair).
__global__ __launch_bounds__(576, 5) void conv_direct(const float* __restrict__ x,
                                                      const ushort_t* __restrict__ Btab,
                                                      const float* __restrict__ wsf,
                                                      float* __restrict__ out) {
  __shared__ __align__(16) char smem[35328];
  ushort_t* As0 = (ushort_t*)smem;                 // 17408 B (8r x 34c x 32ic)
  ushort_t* As1 = (ushort_t*)(smem + 17408);       // 17408 B
  float* ytile  = (float*)smem;                    // 18432 B, overlays As0/As1 (dead at scatter)
  float* red    = (float*)(smem + 34816);          // 480 B

  int blk = blockIdx.x;
  // XCD-affinity decode: consecutive blockIdx round-robin XCDs -> blk&7 = xcd.
  int xcd = blk & 7;
  int q = blk >> 3;                 // 0..49
  int n = xcd + 8 * (q / 25);       // 2 images per XCD -> 4MB, fits per-XCD L2
  int cell = q % 25;
  int OD = cell / 5, OH2 = cell % 5;

  int t = threadIdx.x;
  int wv = t >> 6, l = t & 63;
  int mdl = wv / 3, mhp = wv % 3;
  int tt = l & 15, g = l >> 4;

  // ---- staging lane constants: unit = (r, w, 8-ic chunk); 1024 units/plane
  int r1 = t >> 7, w1g = (t >> 2) & 31, ich1 = t & 3;       // unit1 (all threads), r1 in [0,4]
  int h1 = 6 * OH2 + r1 - 1;
  float msk1 = (h1 >= 0) ? 1.f : 0.f;
  const float* xb1 = x + (size_t)(n * 32 + ich1 * 8) * CHSTR + (h1 > 0 ? h1 : 0) * 32 + w1g;
  int lds1 = (r1 * 34 + w1g + 1) * 32 + ich1 * 8;
  bool has2 = (wv < 7);                                      // wave-uniform!
  int u2 = t + 576;
  int r2 = u2 >> 7, w2g = (u2 >> 2) & 31, ich2 = u2 & 3;     // r2 in [4,7] -> h2 >= 3 (no mask)
  int h2 = 6 * OH2 + r2 - 1;
  const float* xb2 = x + (size_t)(n * 32 + ich2 * 8) * CHSTR + h2 * 32 + w2g;
  int lds2 = (r2 * 34 + w2g + 1) * 32 + ich2 * 8;

#define LOADU(F, P, DOFF) _Pragma("unroll") \
  for (int j = 0; j < 8; ++j) F[j] = (P)[(size_t)j * CHSTR + (DOFF)];
#define PACKW(DST, OFF, F, M) { uint4 _pk; \
  _pk.x = pk2(F[0] * (M), F[1] * (M)); _pk.y = pk2(F[2] * (M), F[3] * (M)); \
  _pk.z = pk2(F[4] * (M), F[5] * (M)); _pk.w = pk2(F[6] * (M), F[7] * (M)); \
  *(uint4*)&(DST)[OFF] = _pk; }

  // ---- prologue: stage plane 0 (d = 3OD-1; negative only when OD==0)
  {
    int d0 = 3 * OD - 1;
    int doff = (d0 > 0 ? d0 : 0) * 1024;
    float m0 = (d0 >= 0) ? 1.f : 0.f;
    float f1[8], f2[8];
    LOADU(f1, xb1, doff);
    if (has2) LOADU(f2, xb2, doff);
    PACKW(As0, lds1, f1, msk1 * m0);
    if (has2) PACKW(As0, lds2, f2, m0);
    if (t < 128) {                   // zero halo cols wpad 0 & 33, both buffers, once
      int bsel = t >> 6, idx = t & 63;
      int rr = idx >> 3, side = (idx >> 2) & 1, qq = idx & 3;
      ushort_t* B = bsel ? As1 : As0;
      *(uint4*)&B[(rr * 34 + (side ? 33 : 0)) * 32 + qq * 8] = make_uint4(0, 0, 0, 0);
    }
  }
  __syncthreads();

  v4f acc[2][2];
#pragma unroll
  for (int m2 = 0; m2 < 2; ++m2)
#pragma unroll
    for (int wh = 0; wh < 2; ++wh) acc[m2][wh] = (v4f){0.f, 0.f, 0.f, 0.f};

  int lane_base = (2 * mhp) * ROW_US + tt * 32 + g * 8;

  for (int p = 0; p < 5; ++p) {
    // ---- T14: issue next plane's loads early (d = 3OD+p >= 0 always in loop)
    float pf1[8], pf2[8];
    if (p < 4) {
      int doff = (3 * OD + p) * 1024;
      LOADU(pf1, xb1, doff);
      if (has2) LOADU(pf2, xb2, doff);
    }

    // ---- compute phase p (R11 core, verified): active if a = mdl+2-p in [0,2]
    int a = mdl + 2 - p;
    if (0 <= a && a <= 2) {
      const ushort_t* Ab = (p & 1) ? As1 : As0;
      const ushort_t* Bg = Btab + ((size_t)(a * 9) * 64 + l) * 8;
#pragma unroll
      for (int c = 0; c < 3; ++c) {
        v8s bv0 = *(const v8s*)(Bg + (0 * 3 + c) * 512);
        v8s bv1 = *(const v8s*)(Bg + (1 * 3 + c) * 512);
        v8s bv2 = *(const v8s*)(Bg + (2 * 3 + c) * 512);
#pragma unroll
        for (int wh = 0; wh < 2; ++wh) {
          const ushort_t* ap = Ab + lane_base + (2 - c + 16 * wh) * 32;
          v8s a0 = *(const v8s*)(ap);
          v8s a1 = *(const v8s*)(ap + 1 * ROW_US);
          v8s a2 = *(const v8s*)(ap + 2 * ROW_US);
          v8s a3 = *(const v8s*)(ap + 3 * ROW_US);
          // row j feeds (m2=0, b=2-j) and (m2=1, b=3-j)
          acc[0][wh] = __builtin_amdgcn_mfma_f32_16x16x32_bf16(a0, bv2, acc[0][wh], 0, 0, 0);
          acc[0][wh] = __builtin_amdgcn_mfma_f32_16x16x32_bf16(a1, bv1, acc[0][wh], 0, 0, 0);
          acc[0][wh] = __builtin_amdgcn_mfma_f32_16x16x32_bf16(a2, bv0, acc[0][wh], 0, 0, 0);
          acc[1][wh] = __builtin_amdgcn_mfma_f32_16x16x32_bf16(a1, bv2, acc[1][wh], 0, 0, 0);
          acc[1][wh] = __builtin_amdgcn_mfma_f32_16x16x32_bf16(a2, bv1, acc[1][wh], 0, 0, 0);
          acc[1][wh] = __builtin_amdgcn_mfma_f32_16x16x32_bf16(a3, bv0, acc[1][wh], 0, 0, 0);
        }
      }
    }

    // ---- pack + write next plane into other buffer, one barrier
    if (p < 4) {
      ushort_t* dst = (p & 1) ? As0 : As1;
      PACKW(dst, lds1, pf1, msk1);
      if (has2) PACKW(dst, lds2, pf2, 1.f);
      __syncthreads();
    }
  }

  // ---- D scatter to ytile (C/D layout verified R6)
  __syncthreads();
  if (tt < 8) {
    int td = tt & 1, th = (tt >> 1) & 1, tw = tt >> 2;
    int odl = 2 * mdl + td;
#pragma unroll
    for (int m2 = 0; m2 < 2; ++m2) {
      int ohl = 2 * (2 * mhp + m2) + th;
      float* yrow = &ytile[(odl * 12 + ohl) * 64];
#pragma unroll
      for (int wh = 0; wh < 2; ++wh)
#pragma unroll
        for (int i = 0; i < 4; ++i)
          yrow[2 * (16 * wh + 4 * g + i) + tw] = acc[m2][wh][i];
    }
  }
  __syncthreads();

  // ---- 6^3 pool: 120 threads = (odl 6, p_oh 2, OW 10)
  if (t < 120) {
    int OW = t % 10, p_oh = (t / 10) & 1, odl = t / 20;
    float m = -3.4e38f;
    for (int oh = 0; oh < 6; ++oh)
#pragma unroll
      for (int j = 0; j < 6; ++j)
        m = fmaxf(m, ytile[(odl * 12 + 6 * p_oh + oh) * 64 + 6 * OW + j]);
    red[t] = m;
  }
  __syncthreads();
  if (t < 20) {
    int OW = t % 10, p_oh = t / 10;
    float m = red[p_oh * 10 + OW];
#pragma unroll
    for (int odl = 1; odl < 6; ++odl) m = fmaxf(m, red[odl * 20 + p_oh * 10 + OW]);
    out[((n * 5 + OD) * 10 + (2 * OH2 + p_oh)) * 10 + OW] = m + wsf[4096];
  }
}

// ================= fallback: R5 verified fp32 path (tiny ws) ===========
__global__ __launch_bounds__(128) void prep2(const float* __restrict__ w,
                                             const float* __restrict__ bias,
                                             float* __restrict__ ws, int woff) {
  int i = blockIdx.x, t = threadIdx.x;
  if (t < 125) {
    const float* wp = w + (size_t)i * 64 * 125 + t;
    float v = 0.f;
#pragma unroll
    for (int o = 0; o < 64; ++o) v += wp[o * 125];
    ws[woff + i * 128 + t] = v;
  }
  if (i == 0 && t == 126) {
    float b = 0.f;
    for (int o = 0; o < 64; ++o) b += bias[o];
    ws[woff + 4096] = b;
  }
}

__global__ __launch_bounds__(256, 4) void conv_stage1(const float* __restrict__ x,
                                                      const float* __restrict__ ws,
                                                      float* part, int woff) {
  __shared__ __align__(16) float xs[170 * XSTR];
  int blk = blockIdx.x;
  int s0 = blk % 320;
  int wq = s0 & 1, hq = (s0 >> 1) & 1, dc = (s0 >> 2) % 5, n = s0 / 20;
  int t = threadIdx.x;
  int mw = t % 15, lmh = t / 15;
  int id_base = 3 * dc - 1, ih_base = 15 * hq - 1;
  int iwb = wq ? 12 : -4;
  int cb = mw + (wq ? 2 : 3);
  const float* xn = x + (size_t)n * NSTRIDE;
  const float* wsw = ws + woff;
  float acc[3][2][2][2] = {{{{0.f}}}};
  for (int phs = 0; phs < 16; ++phs) {
    for (int s = t; s < 1700; s += 256) {
      int c2 = s % 10, row = s / 10;
      int bh = row % 17, q = row / 17;
      int ad = q % 5, lic = q / 5;
      int id = id_base + ad, ih = ih_base + bh, iw = iwb + 2 * c2;
      float2 v = make_float2(0.f, 0.f);
      if ((id | ih | iw) >= 0)
        v = *(const float2*)&xn[(size_t)(phs * 2 + lic) * CHSTR + (id * 32 + ih) * 32 + iw];
      *(float2*)&xs[row * XSTR + 2 * c2] = v;
    }
    __syncthreads();
    if (t < 225) {
#pragma unroll
      for (int lic = 0; lic < 2; ++lic) {
        const float* wc = wsw + (size_t)(phs * 2 + lic) * 128;
        const float* xc = &xs[(lic * 85 + lmh) * XSTR + cb];
        float xv[5][3][3];
#pragma unroll
        for (int a = 0; a < 5; ++a)
#pragma unroll
          for (int b = 0; b < 3; ++b) {
            const float* xr = xc + (a * 17 + b) * XSTR;
            xv[a][b][0] = xr[0]; xv[a][b][1] = xr[1]; xv[a][b][2] = xr[2];
          }
#pragma unroll
        for (int kd = 0; kd < 5; ++kd) {
          constexpr int DT[5] = {0, 1, 0, 1, 0};
          constexpr int AOFF[5] = {2, 2, 1, 1, 0};
          const int dt = DT[kd], aoff = AOFF[kd];
          float wvv[25];
#pragma unroll
          for (int j = 0; j < 25; ++j) wvv[j] = wc[kd * 25 + j];
#pragma unroll
          for (int kh = 0; kh < 5; ++kh) {
            constexpr int HT[5] = {0, 1, 0, 1, 0};
            constexpr int BOFF[5] = {2, 2, 1, 1, 0};
            const int ht = HT[kh], boff = BOFF[kh];
#pragma unroll
            for (int m = 0; m < 3; ++m) {
              const float x0 = xv[m + aoff][boff][0];
              const float x1 = xv[m + aoff][boff][1];
              const float x2 = xv[m + aoff][boff][2];
              acc[m][dt][ht][0] += x0 * wvv[kh * 5 + 4];
              acc[m][dt][ht][0] += x1 * wvv[kh * 5 + 2];
              acc[m][dt][ht][0] += x2 * wvv[kh * 5 + 0];
              acc[m][dt][ht][1] += x1 * wvv[kh * 5 + 3];
              acc[m][dt][ht][1] += x2 * wvv[kh * 5 + 1];
            }
          }
        }
      }
    }
    __syncthreads();
  }
  if (t < 225) {
    float* pb = part + (size_t)n * Y_N;
#pragma unroll
    for (int m = 0; m < 3; ++m)
#pragma unroll
      for (int dt = 0; dt < 2; ++dt)
#pragma unroll
        for (int ht = 0; ht < 2; ++ht) {
          int od_g = 6 * dc + 2 * m + dt;
          int oh_g = 30 * hq + 2 * lmh + ht;
          int ow_g = 30 * wq + 2 * mw;
          *(float2*)&pb[(od_g * 60 + oh_g) * 60 + ow_g] =
              make_float2(acc[m][dt][ht][0], acc[m][dt][ht][1]);
        }
  }
}

__global__ __launch_bounds__(256) void pool_stage2(const float* __restrict__ part,
                                                   const float* __restrict__ ws,
                                                   float* __restrict__ out, int woff) {
  __shared__ __align__(16) float buf[2160];
  __shared__ float red[240];
  int blk = blockIdx.x;
  int hc = blk % 10, dc = (blk / 10) % 5, n = blk / 50;
  int t = threadIdx.x;
  const float* pb = part + (size_t)n * Y_N;
  for (int s = t; s < 540; s += 256) {
    int row = s / 15, c4 = s % 15;
    int od = row / 6, oh = row % 6;
    size_t idx = (size_t)((6 * dc + od) * 60 + (6 * hc + oh)) * 60 + 4 * c4;
    *(float4*)&buf[row * 60 + 4 * c4] = *(const float4*)&pb[idx];
  }
  __syncthreads();
  if (t < 240) {
    int wc = t / 24, sub = t % 24;
    float m = -3.4e38f;
#pragma unroll
    for (int k = 0; k < 9; ++k) {
      int e = sub + 24 * k;
      int od = e / 36, r = e % 36;
      int oh = r / 6, ow0 = r % 6;
      m = fmaxf(m, buf[(od * 6 + oh) * 60 + 6 * wc + ow0]);
    }
    red[t] = m;
  }
  __syncthreads();
  if (t < 10) {
    float mm = -3.4e38f;
#pragma unroll
    for (int s2 = 0; s2 < 24; ++s2) mm = fmaxf(mm, red[t * 24 + s2]);
    out[((n * 5 + dc) * 10 + hc) * 10 + t] = mm + ws[woff + 4096];
  }
}

// ---------------- launch ----------------------------------------------
extern "C" void kernel_launch(void* const* d_in, const int* in_sizes, int n_in,
                              void* d_out, int out_size, void* d_ws, size_t ws_size,
                              hipStream_t stream) {
  const float* x    = (const float*)d_in[0];
  const float* w    = (const float*)d_in[1];
  const float* bias = (const float*)d_in[2];
  float* outp = (float*)d_out;

  if (ws_size >= (size_t)NEED_FUSED) {
    ushort_t* Bt = (ushort_t*)d_ws;
    float* wsf   = (float*)((char*)d_ws + WSF_BYTE_OFF);
    prep_bw<<<27, 256, 0, stream>>>(w, bias, Bt, wsf);
    conv_direct<<<400, 576, 0, stream>>>(x, Bt, wsf, outp);
    return;
  }

  // fp32 fallback (needs ~6.9 MB ws)
  float* ws = (float*)d_ws;
  const size_t need1 = ((size_t)1 * Y_TOT + 4097) * 4;
  if (ws_size >= need1) {
    int woff = Y_TOT;
    prep2<<<32, 128, 0, stream>>>(w, bias, ws, woff);
    conv_stage1<<<320, 256, 0, stream>>>(x, ws, ws, woff);
    pool_stage2<<<800, 256, 0, stream>>>(ws, ws, outp, woff);
  }
}